// Round 3
// baseline (719.633 us; speedup 1.0000x reference)
//
#include <hip/hip_runtime.h>
#include <math.h>

#define GN  4
#define MCN 100
#define BN  512
#define INN 456
#define HN  400
#define ON  10

// softplus(s)^2, numerically stable
__device__ __forceinline__ float sp2f(float s) {
    float l = log1pf(__expf(-fabsf(s)));
    float r = fmaxf(s, 0.0f) + l;
    return r * r;
}

// ---------------- kernel: zero the output (atomicAdd target) ----------------
__global__ __launch_bounds__(256) void k_zero(float* __restrict__ out) {
    int i = blockIdx.x * 256 + threadIdx.x;
    if (i < BN * GN * ON) out[i] = 0.0f;
}

// ---------------- kernel 0a: x -> xT, x^2 -> xxT (tiled transpose) ----------------
__global__ __launch_bounds__(256) void k_transpose(
    const float* __restrict__ x, float* __restrict__ xT, float* __restrict__ xxT) {
    __shared__ float tile[64][65];
    int it = blockIdx.x;           // i tile (8 tiles, tail: 456 = 7*64 + 8)
    int bt = blockIdx.y;           // b tile (8 tiles of 64)
    int tx = threadIdx.x & 63;
    int ty = threadIdx.x >> 6;     // 0..3
    int i_in = it * 64 + tx;
    #pragma unroll
    for (int r = 0; r < 16; ++r) {
        int row = r * 4 + ty;
        int b = bt * 64 + row;
        tile[row][tx] = (i_in < INN) ? x[b * INN + i_in] : 0.0f;
    }
    __syncthreads();
    #pragma unroll
    for (int r = 0; r < 16; ++r) {
        int row = r * 4 + ty;
        int i = it * 64 + row;
        if (i < INN) {
            float v = tile[tx][row];           // stride 65 -> conflict-free
            xT[i * BN + bt * 64 + tx]  = v;
            xxT[i * BN + bt * 64 + tx] = v * v;
        }
    }
}

// ---------------- kernel 0b: sp1 = softplus(sigma1)^2 ----------------
__global__ __launch_bounds__(256) void k_sp1(
    const float* __restrict__ sigma1, float* __restrict__ sp1) {
    int idx = blockIdx.x * 256 + threadIdx.x;
    const int n4 = GN * INN * HN / 4;   // 182400
    if (idx < n4) {
        float4 s = ((const float4*)sigma1)[idx];
        float4 o;
        o.x = sp2f(s.x); o.y = sp2f(s.y); o.z = sp2f(s.z); o.w = sp2f(s.w);
        ((float4*)sp1)[idx] = o;
    }
}

// ---------------- kernel 1: A = x@mu1, S = sqrt((x*x)@sp1) ----------------
// lane = h (coalesced mu1/sp1 dword loads). 4 b's/thread via same-address
// per-lane float4 loads (L1 broadcast, vmcnt-pipelined -- NOT readfirstlane:
// SMEM results need lgkmcnt(0) full drains, which serialized Round-2).
__global__ __launch_bounds__(256, 4) void k_layer1(
    const float* __restrict__ xT, const float* __restrict__ xxT,
    const float* __restrict__ mu1, const float* __restrict__ sp1,
    float* __restrict__ A, float* __restrict__ S) {
    int bt = blockIdx.x;            // 0..31
    int ht = blockIdx.y;            // 0..6
    int g  = blockIdx.z;            // 0..3
    int lane = threadIdx.x & 63;
    int wv   = threadIdx.x >> 6;    // 0..3
    int h = ht * 64 + lane;
    bool hv = h < HN;
    int hc = hv ? h : (HN - 1);     // clamp so masked lanes stay in-bounds
    int b0 = bt * 16 + wv * 4;      // 16B-aligned float4 index
    const float* mp = mu1 + (size_t)g * INN * HN + hc;
    const float* pp = sp1 + (size_t)g * INN * HN + hc;
    float accA[4] = {0.f, 0.f, 0.f, 0.f};
    float accD[4] = {0.f, 0.f, 0.f, 0.f};
    #pragma unroll 8
    for (int k = 0; k < INN; ++k) {       // 456 = 57*8
        float a = mp[(size_t)k * HN];
        float p = pp[(size_t)k * HN];
        float4 xv  = *(const float4*)(xT  + k * BN + b0);
        float4 xxv = *(const float4*)(xxT + k * BN + b0);
        accA[0] = fmaf(a, xv.x,  accA[0]);
        accA[1] = fmaf(a, xv.y,  accA[1]);
        accA[2] = fmaf(a, xv.z,  accA[2]);
        accA[3] = fmaf(a, xv.w,  accA[3]);
        accD[0] = fmaf(p, xxv.x, accD[0]);
        accD[1] = fmaf(p, xxv.y, accD[1]);
        accD[2] = fmaf(p, xxv.z, accD[2]);
        accD[3] = fmaf(p, xxv.w, accD[3]);
    }
    if (hv) {
        #pragma unroll
        for (int j = 0; j < 4; ++j) {
            size_t o = ((size_t)g * BN + (b0 + j)) * HN + h;
            A[o] = accA[j];
            S[o] = sqrtf(accD[j]);
        }
    }
}

// ---------------- kernel 2: layer 2 + softmax + MC mean ----------------
// og-split: block = 512 threads = 2 halves x (16 rg x 16 kc). og=0 accumulates
// g3 (weights w_s), og=1 accumulates d3 (weights v_s, operand hval^2).
// Only 40 acc regs/thread -> no spill under __launch_bounds__(512,4) (128-reg
// budget), 16 waves/CU. Weight rows padded to 12 floats: 16B-aligned b128
// reads, 2-way bank aliasing (free per m136). zeta1 loads duplicated across
// halves (L1 broadcast). sqrt(d3) crosses halves via LDS for the epilogue.
template <int TM, bool SQ>
__device__ __forceinline__ void l2_loop(
    const float* __restrict__ as_s, const float* __restrict__ wb,
    const float* const (&zp)[TM], int kc, float (&acc)[TM][ON]) {
    float zc[TM];
    #pragma unroll
    for (int i = 0; i < TM; ++i) zc[i] = zp[i][0];
    #pragma unroll 1
    for (int j = 0; j < 25; ++j) {
        float zn[TM];
        if (j < 24) {
            #pragma unroll
            for (int i = 0; i < TM; ++i) zn[i] = zp[i][16 * (j + 1)];
        } else {
            #pragma unroll
            for (int i = 0; i < TM; ++i) zn[i] = 0.0f;
        }
        int k = kc + 16 * j;
        float2 as = *(const float2*)(as_s + 2 * k);
        const float* wr = wb + k * 12;
        float4 wa = *(const float4*)(wr);
        float4 wv = *(const float4*)(wr + 4);
        float2 wc = *(const float2*)(wr + 8);
        #pragma unroll
        for (int i = 0; i < TM; ++i) {
            float hv = fmaxf(0.0f, fmaf(as.y, zc[i], as.x));
            float e = SQ ? hv * hv : hv;
            acc[i][0] = fmaf(e, wa.x, acc[i][0]);
            acc[i][1] = fmaf(e, wa.y, acc[i][1]);
            acc[i][2] = fmaf(e, wa.z, acc[i][2]);
            acc[i][3] = fmaf(e, wa.w, acc[i][3]);
            acc[i][4] = fmaf(e, wv.x, acc[i][4]);
            acc[i][5] = fmaf(e, wv.y, acc[i][5]);
            acc[i][6] = fmaf(e, wv.z, acc[i][6]);
            acc[i][7] = fmaf(e, wv.w, acc[i][7]);
            acc[i][8] = fmaf(e, wc.x, acc[i][8]);
            acc[i][9] = fmaf(e, wc.y, acc[i][9]);
        }
        #pragma unroll
        for (int i = 0; i < TM; ++i) zc[i] = zn[i];
    }
}

template <int TM>
__global__ __launch_bounds__(512, 4) void k_layer2(
    int mb,
    const float* __restrict__ A, const float* __restrict__ S,
    const float* __restrict__ mu3, const float* __restrict__ sigma3,
    const float* __restrict__ zeta1, const float* __restrict__ zeta3,
    float* __restrict__ out) {
    int b = blockIdx.x;   // 0..511
    int g = blockIdx.y;   // 0..3

    __shared__ float as_s[2 * HN];       // 3.2 KB  [h][2] = {A,S}
    __shared__ float w_s[HN * 12];       // 19.2 KB mu3 rows padded to 12
    __shared__ float v_s[HN * 12];       // 19.2 KB sp2(sigma3) rows padded
    __shared__ float d3x[16][TM][ON];    // sqrt(d3) exchange og1 -> og0
    __shared__ float outsh[16][ON];

    int t = threadIdx.x;

    for (int i = t; i < HN; i += 512) {
        size_t src = ((size_t)g * BN + b) * HN + i;
        as_s[2 * i]     = A[src];
        as_s[2 * i + 1] = S[src];
    }
    for (int i = t; i < HN * ON; i += 512) {
        int h = i / 10, o = i - h * 10;
        size_t src = (size_t)g * HN * ON + i;
        w_s[h * 12 + o] = mu3[src];
        v_s[h * 12 + o] = sp2f(sigma3[src]);
    }
    __syncthreads();

    int og = t >> 8;        // 0: g3 half, 1: d3 half
    int th = t & 255;
    int rg = th >> 4;       // 0..15
    int kc = th & 15;       // 0..15

    float acc[TM][ON];
    #pragma unroll
    for (int i = 0; i < TM; ++i)
        #pragma unroll
        for (int o = 0; o < ON; ++o) acc[i][o] = 0.0f;

    const float* zp[TM];
    #pragma unroll
    for (int i = 0; i < TM; ++i) {
        int m = mb + rg + 16 * i;
        int mcl = m < MCN ? m : (MCN - 1);   // clamp; result discarded
        zp[i] = zeta1 + ((size_t)(g * MCN + mcl) * BN + b) * HN + kc;
    }

    if (og == 0) l2_loop<TM, false>(as_s, w_s, zp, kc, acc);
    else         l2_loop<TM, true >(as_s, v_s, zp, kc, acc);

    // reduce over the 16 kc lanes (butterfly stays inside 16-lane groups)
    #pragma unroll
    for (int i = 0; i < TM; ++i)
        #pragma unroll
        for (int o = 0; o < ON; ++o) {
            float v = acc[i][o];
            v += __shfl_xor(v, 1);
            v += __shfl_xor(v, 2);
            v += __shfl_xor(v, 4);
            v += __shfl_xor(v, 8);
            acc[i][o] = v;
        }

    if (og == 1 && kc == 0) {
        #pragma unroll
        for (int i = 0; i < TM; ++i)
            #pragma unroll
            for (int o = 0; o < ON; ++o) d3x[rg][i][o] = sqrtf(acc[i][o]);
    }
    __syncthreads();

    // epilogue on og=0 kc==0 lanes: relu(g3 + sqrt(d3)*z3), softmax, MC-sum
    if (og == 0 && kc == 0) {
        float psum[ON];
        #pragma unroll
        for (int o = 0; o < ON; ++o) psum[o] = 0.0f;
        #pragma unroll
        for (int i = 0; i < TM; ++i) {
            int m = mb + rg + 16 * i;
            if (m < MCN) {
                const float* z3p = zeta3 + ((size_t)(g * MCN + m) * BN + b) * ON;
                float ov[ON];
                float mx = 0.0f;
                #pragma unroll
                for (int o = 0; o < ON; ++o) {
                    float v = fmaf(d3x[rg][i][o], z3p[o], acc[i][o]);
                    v = fmaxf(v, 0.0f);
                    ov[o] = v;
                    mx = fmaxf(mx, v);
                }
                float se = 0.0f;
                #pragma unroll
                for (int o = 0; o < ON; ++o) { float e = __expf(ov[o] - mx); ov[o] = e; se += e; }
                float r = 1.0f / se;
                #pragma unroll
                for (int o = 0; o < ON; ++o) psum[o] = fmaf(ov[o], r, psum[o]);
            }
        }
        #pragma unroll
        for (int o = 0; o < ON; ++o) outsh[rg][o] = psum[o];
    }
    __syncthreads();
    if (t < ON) {
        float s = 0.0f;
        #pragma unroll
        for (int r = 0; r < 16; ++r) s += outsh[r][t];
        atomicAdd(&out[b * (GN * ON) + g * ON + t], s * (1.0f / MCN));
    }
}

extern "C" void kernel_launch(void* const* d_in, const int* in_sizes, int n_in,
                              void* d_out, int out_size, void* d_ws, size_t ws_size,
                              hipStream_t stream) {
    const float* x      = (const float*)d_in[0];
    const float* mu1    = (const float*)d_in[1];
    const float* sigma1 = (const float*)d_in[2];
    const float* mu3    = (const float*)d_in[3];
    const float* sigma3 = (const float*)d_in[4];
    const float* zeta1  = (const float*)d_in[5];
    const float* zeta3  = (const float*)d_in[6];
    // d_in[7] = num (always 3 -> G = 4, baked into GN)

    float* ws  = (float*)d_ws;
    float* xT  = ws;                       // 456*512  = 233472
    float* xxT = xT  + INN * BN;           // 233472
    float* sp1 = xxT + INN * BN;           // 4*456*400 = 729600
    float* A   = sp1 + GN * INN * HN;      // 4*512*400 = 819200
    float* S   = A   + GN * BN * HN;       // 819200
    float* out = (float*)d_out;            // 512*40

    k_zero<<<dim3((BN * GN * ON + 255) / 256), 256, 0, stream>>>(out);
    k_transpose<<<dim3(8, 8), 256, 0, stream>>>(x, xT, xxT);
    k_sp1<<<dim3((GN * INN * HN / 4 + 255) / 256), 256, 0, stream>>>(sigma1, sp1);
    k_layer1<<<dim3(32, 7, GN), 256, 0, stream>>>(xT, xxT, mu1, sp1, A, S);
    // MC rows 0..63 (TM=4) and 64..99 (TM=3, 12 clamped slots)
    k_layer2<4><<<dim3(BN, GN), 512, 0, stream>>>(0,  A, S, mu3, sigma3, zeta1, zeta3, out);
    k_layer2<3><<<dim3(BN, GN), 512, 0, stream>>>(64, A, S, mu3, sigma3, zeta1, zeta3, out);
}